// Round 4
// baseline (378.121 us; speedup 1.0000x reference)
//
#include <hip/hip_runtime.h>
#include <hip/hip_bf16.h>

typedef __attribute__((ext_vector_type(8))) short short8;
typedef __attribute__((ext_vector_type(4))) float float4v;

static __device__ __forceinline__ unsigned short f2bf(float f) {
    unsigned u = __float_as_uint(f);
    unsigned r = (u + 0x7FFF + ((u >> 16) & 1)) >> 16;  // RNE
    return (unsigned short)r;
}

// ---------------------------------------------------------------------------
// Build dense (Co,Ci,5,5) kernel from DCLS weights/positions via atomic scatter.
__global__ void build_dcls(const float* __restrict__ w, const float* __restrict__ p,
                           float* __restrict__ K, int total, int Kc) {
    for (int idx = blockIdx.x * blockDim.x + threadIdx.x; idx < total;
         idx += gridDim.x * blockDim.x) {
        float wv = w[idx];
        float pa = p[idx];
        float pb = p[total + idx];
        float pos1 = fminf(fmaxf(pa, -2.f), 2.f) + 2.f;
        float pos2 = fminf(fmaxf(pb, -2.f), 2.f) + 2.f;
        int i1 = (int)floorf(pos1);
        int i2 = (int)floorf(pos2);
        float r1 = pos1 - (float)i1;
        float r2 = pos2 - (float)i2;
        int cell = idx / Kc;
        float* Kb = K + cell * 25;
        atomicAdd(&Kb[i1 * 5 + i2], wv * (1.f - r1) * (1.f - r2));
        if (i1 + 1 < 5) atomicAdd(&Kb[(i1 + 1) * 5 + i2], wv * r1 * (1.f - r2));
        if (i2 + 1 < 5) atomicAdd(&Kb[i1 * 5 + i2 + 1], wv * (1.f - r1) * r2);
        if (i1 + 1 < 5 && i2 + 1 < 5) atomicAdd(&Kb[(i1 + 1) * 5 + i2 + 1], wv * r1 * r2);
    }
}

// K2f (64,32,5,5) fp32 -> Kt[kk][co][ci] bf16
__global__ void prep_kt(const float* __restrict__ K2f, unsigned short* __restrict__ Kt) {
    int idx = blockIdx.x * blockDim.x + threadIdx.x;
    if (idx < 25 * 64 * 32) {
        int kk = idx >> 11;
        int co = (idx >> 5) & 63;
        int ci = idx & 31;
        Kt[idx] = f2bf(K2f[(co * 32 + ci) * 25 + kk]);
    }
}

// K1f (32,25) fp32 -> K1a[half][co][32] bf16 tap layout:
// k = rowgrp*8 + kx;  half0: window rows 0..3 (=ky), half1: rows 4..7 (only row 4 real)
__global__ void prep_k1a(const float* __restrict__ K1f, unsigned short* __restrict__ K1a) {
    int idx = blockIdx.x * blockDim.x + threadIdx.x;
    if (idx < 2 * 32 * 32) {
        int half = idx >> 10;
        int co = (idx >> 5) & 31;
        int k = idx & 31;
        int ky = (k >> 3) + half * 4;
        int kx = k & 7;
        float v = (kx < 5 && ky < 5) ? K1f[co * 25 + ky * 5 + kx] : 0.f;
        K1a[idx] = f2bf(v);
    }
}

// fc1_w (128,3136) fp32 -> bf16 (same layout = B-fragment friendly)
__global__ void prep_w1b(const float* __restrict__ w, unsigned short* __restrict__ wb,
                         int total) {
    int idx = blockIdx.x * blockDim.x + threadIdx.x;
    if (idx < total) wb[idx] = f2bf(w[idx]);
}

// ---------------------------------------------------------------------------
// Fused conv: both convs on MFMA.
// conv1: K=64 taps (8 rows x 8 kx, zero-padded weights) = 2 MFMAs; B-frag = one
//        ds_read_b128 of an image row, via 8 phase-shifted bf16 LDS copies.
// conv2: shift-GEMM over 25 taps, K=32 ci (as R3).
// Both epilogues: in-register 2x2 maxpool via shfl xor1/xor8.
// One block (4 waves) per image; LDS ~52.6 KB -> 3 blocks/CU.
// ---------------------------------------------------------------------------
__global__ __launch_bounds__(256, 3) void fused_conv_mfma(
    const float* __restrict__ x,             // (B,1,28,28)
    const unsigned short* __restrict__ K1a,  // (2,32,32) bf16 tap layout
    const unsigned short* __restrict__ Kt,   // (25,64,32) bf16
    const float* __restrict__ b1,
    const float* __restrict__ b2,
    unsigned short* __restrict__ h2) {       // (B,64,7,7) bf16
    __shared__ __align__(16) unsigned short sm_xb[784];          // bf16 image
    __shared__ __align__(16) unsigned short sm8[8 * 29 * 48];    // 8 shifted copies; row 28 = zeros
    __shared__ __align__(16) unsigned short h1p[18 * 20 * 40];   // [yy][xx][ci(+pad)]

    const int b = blockIdx.x;
    const int tid = threadIdx.x;
    const int lane = tid & 63;
    const int wv = tid >> 6;
    const int n16 = lane & 15;
    const int cig = lane >> 4;

    // zero h1p (border + pad lanes must be 0)
    for (int t = tid; t < 1800; t += 256) ((uint4*)h1p)[t] = uint4{0, 0, 0, 0};
    // stage image as bf16 (single conversion point)
    const float* xb = x + (size_t)b * 784;
    for (int t = tid; t < 784; t += 256) sm_xb[t] = f2bf(xb[t]);
    __syncthreads();

    // ---- build 8 shifted copies: copy s, row r (29 rows; r==28 all-zero) ----
    // position p in copy s holds pixel col c = p + s - 8 (zero outside 0..27)
    if (tid < 232) {
        int s = tid / 29;
        int r = tid - s * 29;
        unsigned short* dst = sm8 + (s * 29 + r) * 48;
        bool rok = r < 28;
#pragma unroll
        for (int g = 0; g < 6; ++g) {
            short8 v;
#pragma unroll
            for (int e = 0; e < 8; ++e) {
                int c = g * 8 + e + s - 8;
                unsigned short val =
                    (rok && (unsigned)c < 28u) ? sm_xb[r * 28 + c] : (unsigned short)0;
                v[e] = (short)val;
            }
            ((short8*)dst)[g] = v;
        }
    }

    // A-fragments + biases for conv1 (global, L2-hot)
    short8 a1[2], a2[2];
    float bias1[2][4];
#pragma unroll
    for (int cot = 0; cot < 2; ++cot) {
        a1[cot] = *(const short8*)(K1a + (0 * 32 + cot * 16 + n16) * 32 + cig * 8);
        a2[cot] = *(const short8*)(K1a + (1 * 32 + cot * 16 + n16) * 32 + cig * 8);
#pragma unroll
        for (int r = 0; r < 4; ++r) bias1[cot][r] = b1[cot * 16 + 4 * cig + r];
    }
    __syncthreads();

    // ---- conv1 MFMA: 56 n-tiles (14 row-pairs x 4 col-halves of 8), wave-split ----
    {
        const int y = (n16 >> 3);        // row within pair
        const int xl = (n16 & 7);
#pragma unroll 2
        for (int t14 = 0; t14 < 14; ++t14) {
            int t = wv + 4 * t14;        // 0..55
            int ty = t >> 2;             // pos row pair 0..13
            int xh = t & 3;              // col half 0..3
            int yy = 2 * ty + y;         // pos row 0..27
            int xx = 8 * xh + xl;        // pos col 0..31 (28..31 phantom)
            int c0 = xx - 2;
            int s = (c0 + 8) & 7;
            int p0 = (c0 + 8) & ~7;
            const unsigned short* base = sm8 + s * 1392 + p0;
            int row1 = yy - 2 + cig;     // window rows 0..3
            int row2 = yy + 2 + cig;     // window rows 4..7
            int r1 = ((unsigned)row1 < 28u) ? row1 : 28;  // 28 = zero row
            int r2 = ((unsigned)row2 < 28u) ? row2 : 28;
            short8 bf1 = *(const short8*)(base + r1 * 48);
            short8 bf2 = *(const short8*)(base + r2 * 48);

            float4v acc[2];
#pragma unroll
            for (int cot = 0; cot < 2; ++cot) {
                acc[cot] = float4v{0.f, 0.f, 0.f, 0.f};
                acc[cot] = __builtin_amdgcn_mfma_f32_16x16x32_bf16(a1[cot], bf1, acc[cot], 0, 0, 0);
                acc[cot] = __builtin_amdgcn_mfma_f32_16x16x32_bf16(a2[cot], bf2, acc[cot], 0, 0, 0);
            }
            // pool 2x2 (shfl xor1 = x-pair, xor8 = y-pair), write h1p bf16
#pragma unroll
            for (int cot = 0; cot < 2; ++cot) {
#pragma unroll
                for (int r = 0; r < 4; ++r) {
                    float v = acc[cot][r];
                    v = fmaxf(v, __shfl_xor(v, 1));
                    v = fmaxf(v, __shfl_xor(v, 8));
                    if ((n16 & 9) == 0) {
                        int xo = 4 * xh + (n16 >> 1);   // pooled col 0..15
                        if (xo < 14) {
                            int co = cot * 16 + 4 * cig + r;
                            h1p[((ty + 2) * 20 + (xo + 2)) * 40 + co] =
                                f2bf(fmaxf(v + bias1[cot][r], 0.f));
                        }
                    }
                }
            }
        }
    }
    __syncthreads();

    // ---- conv2: wave wv handles nt in {wv, wv+4, wv+8, wv+12} (nt<14) ----
    int ybase[4], xbase[4], ty_a[4], xh_a[4];
    bool valid[4];
#pragma unroll
    for (int ntl = 0; ntl < 4; ++ntl) {
        int nt = wv + 4 * ntl;
        valid[ntl] = nt < 14;
        int nts = valid[ntl] ? nt : 0;
        int ty = nts >> 1, xh = nts & 1;
        ty_a[ntl] = ty; xh_a[ntl] = xh;
        ybase[ntl] = 2 * ty + (n16 >> 3);
        xbase[ntl] = 8 * xh + (n16 & 7);
    }

    float4v acc[4][4];  // [ntl][cot]
#pragma unroll
    for (int i = 0; i < 4; ++i)
#pragma unroll
        for (int c = 0; c < 4; ++c) acc[i][c] = float4v{0.f, 0.f, 0.f, 0.f};

#pragma unroll
    for (int ky = 0; ky < 5; ++ky) {
#pragma unroll
        for (int kx = 0; kx < 5; ++kx) {
            int kk = ky * 5 + kx;
            short8 afr[4];
#pragma unroll
            for (int cot = 0; cot < 4; ++cot)
                afr[cot] = *(const short8*)(Kt + ((kk * 64 + cot * 16 + n16) * 32 + cig * 8));
#pragma unroll
            for (int ntl = 0; ntl < 4; ++ntl) {
                if (valid[ntl]) {
                    short8 bf = *(const short8*)(h1p +
                        ((ybase[ntl] + ky) * 20 + xbase[ntl] + kx) * 40 + cig * 8);
#pragma unroll
                    for (int cot = 0; cot < 4; ++cot)
                        acc[ntl][cot] = __builtin_amdgcn_mfma_f32_16x16x32_bf16(
                            afr[cot], bf, acc[ntl][cot], 0, 0, 0);
                }
            }
        }
    }

    unsigned short* outb = h2 + (size_t)b * 3136;
#pragma unroll
    for (int ntl = 0; ntl < 4; ++ntl) {
        if (valid[ntl]) {
#pragma unroll
            for (int cot = 0; cot < 4; ++cot) {
#pragma unroll
                for (int r = 0; r < 4; ++r) {
                    float v = acc[ntl][cot][r];
                    v = fmaxf(v, __shfl_xor(v, 1));
                    v = fmaxf(v, __shfl_xor(v, 8));
                    if ((n16 & 9) == 0) {
                        int xo = 4 * xh_a[ntl] + (n16 >> 1);
                        if (xo < 7) {
                            int co = cot * 16 + 4 * cig + r;
                            outb[co * 49 + ty_a[ntl] * 7 + xo] =
                                f2bf(fmaxf(v + b2[co], 0.f));
                        }
                    }
                }
            }
        }
    }
}

// ---------------------------------------------------------------------------
// FC1 MFMA: out(B,128) += A(B,3136)bf16 @ W(128,3136)bf16^T  (K-split 7, atomics)
// Block: 16 rows, 4 waves x 32 cols, K-chunk 448 (14 slices). No LDS.
__global__ __launch_bounds__(256) void fc1_mfma(
    const unsigned short* __restrict__ A,   // (B,3136) bf16
    const unsigned short* __restrict__ Wb,  // (128,3136) bf16
    float* __restrict__ out) {              // (B,128) f32, pre-zeroed (bias in fc2)
    const int blk = blockIdx.x;
    const int kh = blk % 7;
    const int m0 = (blk / 7) * 16;
    const int tid = threadIdx.x;
    const int wv = tid >> 6;
    const int lane = tid & 63;
    const int n16 = lane & 15;
    const int cig = lane >> 4;

    const unsigned short* Arow = A + (size_t)(m0 + n16) * 3136 + cig * 8 + kh * 448;
    const unsigned short* W0 = Wb + (size_t)(wv * 32 + n16) * 3136 + cig * 8 + kh * 448;
    const unsigned short* W1 = W0 + 16 * 3136;

    float4v acc0 = {0.f, 0.f, 0.f, 0.f};
    float4v acc1 = {0.f, 0.f, 0.f, 0.f};
#pragma unroll 7
    for (int k = 0; k < 448; k += 32) {
        short8 a = *(const short8*)(Arow + k);
        short8 w0 = *(const short8*)(W0 + k);
        short8 w1 = *(const short8*)(W1 + k);
        acc0 = __builtin_amdgcn_mfma_f32_16x16x32_bf16(a, w0, acc0, 0, 0, 0);
        acc1 = __builtin_amdgcn_mfma_f32_16x16x32_bf16(a, w1, acc1, 0, 0, 0);
    }
#pragma unroll
    for (int r = 0; r < 4; ++r) {
        int row = m0 + cig * 4 + r;
        atomicAdd(&out[(size_t)row * 128 + wv * 32 + n16], acc0[r]);
        atomicAdd(&out[(size_t)row * 128 + wv * 32 + 16 + n16], acc1[r]);
    }
}

// FC2 (fused fc1 bias+relu): out(B,10) = relu(fc1o + fc1b) @ W(10,128)^T + b2
__global__ __launch_bounds__(256) void fc2_kernel(
    const float* __restrict__ A, const float* __restrict__ fc1b,
    const float* __restrict__ W, const float* __restrict__ bias,
    float* __restrict__ out, int total) {
    __shared__ float smW[10 * 132];  // padded stride (kills bank conflicts)
    __shared__ float smB1[128];
    __shared__ float smB[10];
    int t = threadIdx.x;
    for (int i = t; i < 1280; i += 256) {
        int n = i >> 7, k = i & 127;
        smW[n * 132 + k] = W[i];
    }
    if (t < 128) smB1[t] = fc1b[t];
    if (t < 10) smB[t] = bias[t];
    __syncthreads();
    int idx = blockIdx.x * 256 + t;
    if (idx < total) {
        int b = idx / 10;
        int n = idx - b * 10;
        const float4* row = (const float4*)(A + (size_t)b * 128);
        const float4* bb = (const float4*)smB1;
        const float4* wr = (const float4*)(smW + n * 132);
        float acc = smB[n];
#pragma unroll
        for (int k = 0; k < 32; ++k) {
            float4 a = row[k];
            float4 bv = bb[k];
            float4 w = wr[k];
            acc += fmaxf(a.x + bv.x, 0.f) * w.x + fmaxf(a.y + bv.y, 0.f) * w.y +
                   fmaxf(a.z + bv.z, 0.f) * w.z + fmaxf(a.w + bv.w, 0.f) * w.w;
        }
        out[idx] = acc;
    }
}

extern "C" void kernel_launch(void* const* d_in, const int* in_sizes, int n_in,
                              void* d_out, int out_size, void* d_ws, size_t ws_size,
                              hipStream_t stream) {
    const float* x    = (const float*)d_in[0];
    const float* w1   = (const float*)d_in[1];
    const float* p1   = (const float*)d_in[2];
    const float* b1   = (const float*)d_in[3];
    const float* w2   = (const float*)d_in[4];
    const float* p2   = (const float*)d_in[5];
    const float* b2   = (const float*)d_in[6];
    const float* fc1w = (const float*)d_in[7];
    const float* fc1b = (const float*)d_in[8];
    const float* fc2w = (const float*)d_in[9];
    const float* fc2b = (const float*)d_in[10];
    float* out = (float*)d_out;

    const int B = in_sizes[0] / 784;  // 4096

    float* ws = (float*)d_ws;
    float* K1f = ws;                                       // 800 f
    float* K2f = ws + 800;                                 // 51200 f -> end 52000
    unsigned short* Kt  = (unsigned short*)(ws + 52000);   // 51200 bf16 (25600 f)
    unsigned short* K1a = (unsigned short*)(ws + 77600);   // 2048 bf16 (1024 f)
    unsigned short* w1b = (unsigned short*)(ws + 78624);   // 401408 bf16 (200704 f)
    unsigned short* h2b = (unsigned short*)(ws + 279328);  // B*3136 bf16
    float* fc1o = ws + 279328 + (size_t)B * 1568;          // B*128 f32

    hipMemsetAsync(ws, 0, 52000 * sizeof(float), stream);
    hipMemsetAsync(fc1o, 0, (size_t)B * 128 * sizeof(float), stream);

    build_dcls<<<2, 256, 0, stream>>>(w1, p1, K1f, 32 * 1 * 16, 16);
    build_dcls<<<256, 256, 0, stream>>>(w2, p2, K2f, 64 * 32 * 32, 32);
    prep_kt<<<(25 * 64 * 32 + 255) / 256, 256, 0, stream>>>(K2f, Kt);
    prep_k1a<<<(2 * 32 * 32 + 255) / 256, 256, 0, stream>>>(K1f, K1a);
    prep_w1b<<<(128 * 3136 + 255) / 256, 256, 0, stream>>>(fc1w, w1b, 128 * 3136);

    fused_conv_mfma<<<B, 256, 0, stream>>>(x, K1a, Kt, b1, b2, h2b);
    fc1_mfma<<<(B / 16) * 7, 256, 0, stream>>>(h2b, w1b, fc1o);
    fc2_kernel<<<(B * 10 + 255) / 256, 256, 0, stream>>>(fc1o, fc1b, fc2w, fc2b, out, B * 10);
}

// Round 5
// 303.192 us; speedup vs baseline: 1.2471x; 1.2471x over previous
//
#include <hip/hip_runtime.h>
#include <hip/hip_bf16.h>

typedef __attribute__((ext_vector_type(8))) short short8;
typedef __attribute__((ext_vector_type(4))) short short4v;
typedef __attribute__((ext_vector_type(4))) float float4v;

static __device__ __forceinline__ unsigned short f2bf(float f) {
    unsigned u = __float_as_uint(f);
    unsigned r = (u + 0x7FFF + ((u >> 16) & 1)) >> 16;  // RNE
    return (unsigned short)r;
}

// 2x2 max-pool reduce across lanes: xor1 via DPP quad_perm(1,0,3,2),
// xor8 via DPP row_ror:8 — VALU pipe, keeps the LDS pipe free.
static __device__ __forceinline__ float pool_max(float v) {
    int a = __builtin_amdgcn_update_dpp(0, __float_as_int(v), 0xB1, 0xF, 0xF, true);
    v = fmaxf(v, __int_as_float(a));
    int b = __builtin_amdgcn_update_dpp(0, __float_as_int(v), 0x128, 0xF, 0xF, true);
    v = fmaxf(v, __int_as_float(b));
    return v;
}

// ---------------------------------------------------------------------------
// ONE prep kernel (kills ~6 tiny launches):
//  block 0            : K1a[half][co][32] bf16 (gather DCLS, conv1 tap layout)
//  blocks 1..200      : Kt[kk][co][ci] bf16   (gather DCLS conv2)
//  blocks 201..1768   : fc1w fp32 -> bf16 convert
//  blocks 1769..1800  : zero fc1o (for fc1 atomics)
// Gather replaces atomic scatter: cell (y,x) sums matching bilinear corners.
// ---------------------------------------------------------------------------
__global__ __launch_bounds__(256) void prep_all(
    const float* __restrict__ w1, const float* __restrict__ p1,
    const float* __restrict__ w2, const float* __restrict__ p2,
    const float* __restrict__ fc1w,
    unsigned short* __restrict__ K1a,  // (2,32,32)
    unsigned short* __restrict__ Kt,   // (25,64,32)
    unsigned short* __restrict__ w1b,  // (128,3136)
    float* __restrict__ fc1o) {        // (B,128) -> zeroed
    const int blk = blockIdx.x;
    const int t = threadIdx.x;

    if (blk == 0) {
        // K1a: 2048 cells, 8 per thread; taps: k = rowgrp*8+kx, ky = rowgrp+4*half
#pragma unroll
        for (int i = 0; i < 8; ++i) {
            int cell = t + 256 * i;
            int half = cell >> 10;
            int co = (cell >> 5) & 31;
            int k = cell & 31;
            int ky = (k >> 3) + 4 * half;
            int kx = k & 7;
            float acc = 0.f;
            if (kx < 5 && ky < 5) {
                for (int kc = 0; kc < 16; ++kc) {
                    float wv = w1[co * 16 + kc];
                    float pa = p1[co * 16 + kc];
                    float pb = p1[512 + co * 16 + kc];
                    float pos1 = fminf(fmaxf(pa, -2.f), 2.f) + 2.f;
                    float pos2 = fminf(fmaxf(pb, -2.f), 2.f) + 2.f;
                    int i1 = (int)floorf(pos1);
                    int i2 = (int)floorf(pos2);
                    float r1 = pos1 - (float)i1;
                    float r2 = pos2 - (float)i2;
                    float c = 0.f;
                    if (i1 == ky && i2 == kx) c += (1.f - r1) * (1.f - r2);
                    if (i1 + 1 == ky && i2 == kx) c += r1 * (1.f - r2);
                    if (i1 == ky && i2 + 1 == kx) c += (1.f - r1) * r2;
                    if (i1 + 1 == ky && i2 + 1 == kx) c += r1 * r2;
                    acc += wv * c;
                }
            }
            K1a[cell] = f2bf(acc);
        }
    } else if (blk <= 200) {
        // Kt: cell = kk*2048 + co*32 + ci ; gather over 32 kc
        int cell = (blk - 1) * 256 + t;
        int kk = cell >> 11;
        int co = (cell >> 5) & 63;
        int ci = cell & 31;
        int ky = kk / 5;
        int kx = kk - ky * 5;
        const int base = (co * 32 + ci) * 32;
        float acc = 0.f;
        for (int kc = 0; kc < 32; ++kc) {
            float wv = w2[base + kc];
            float pa = p2[base + kc];
            float pb = p2[65536 + base + kc];
            float pos1 = fminf(fmaxf(pa, -2.f), 2.f) + 2.f;
            float pos2 = fminf(fmaxf(pb, -2.f), 2.f) + 2.f;
            int i1 = (int)floorf(pos1);
            int i2 = (int)floorf(pos2);
            float r1 = pos1 - (float)i1;
            float r2 = pos2 - (float)i2;
            float c = 0.f;
            if (i1 == ky && i2 == kx) c += (1.f - r1) * (1.f - r2);
            if (i1 + 1 == ky && i2 == kx) c += r1 * (1.f - r2);
            if (i1 == ky && i2 + 1 == kx) c += (1.f - r1) * r2;
            if (i1 + 1 == ky && i2 + 1 == kx) c += r1 * r2;
            acc += wv * c;
        }
        Kt[cell] = f2bf(acc);
    } else if (blk <= 1768) {
        int idx = (blk - 201) * 256 + t;  // < 401408
        w1b[idx] = f2bf(fc1w[idx]);
    } else {
        int i = (blk - 1769) * 256 + t;
        float4* o = (float4*)fc1o;
#pragma unroll
        for (int j = 0; j < 16; ++j) o[i + j * 8192] = float4{0.f, 0.f, 0.f, 0.f};
    }
}

// ---------------------------------------------------------------------------
// Fused conv, both convs on MFMA. One block (4 waves) per image.
// conv1: K=64 taps (8 rows x 8 kx zero-padded) = 2 MFMAs/tile; B-frag = 8
//   contiguous bf16 of an image row via 4 phase-shifted LDS copies (2x b64).
// conv2: 25-tap shift-GEMM, K=32 ci. Pooling in-register via DPP.
// LDS 40.5 KB -> 4 blocks/CU; launch_bounds(256,4) -> regs fit 4 waves/SIMD.
// ---------------------------------------------------------------------------
__global__ __launch_bounds__(256, 4) void fused_conv_mfma(
    const float* __restrict__ x,             // (B,1,28,28)
    const unsigned short* __restrict__ K1a,  // (2,32,32)
    const unsigned short* __restrict__ Kt,   // (25,64,32)
    const float* __restrict__ b1,
    const float* __restrict__ b2,
    unsigned short* __restrict__ h2) {       // (B,64,7,7) bf16
    __shared__ __align__(16) unsigned short sm_xb[784];          // bf16 image
    __shared__ __align__(16) unsigned short sm4[4 * 29 * 44];    // 4 shifted copies; row 28 zero
    __shared__ __align__(16) unsigned short h1p[18 * 20 * 40];   // [yy][xx][ci(+pad)]

    const int b = blockIdx.x;
    const int tid = threadIdx.x;
    const int lane = tid & 63;
    const int wv = tid >> 6;
    const int n16 = lane & 15;
    const int cig = lane >> 4;

    // zero h1p borders (+pad), stage image bf16
    for (int t = tid; t < 1800; t += 256) ((uint4*)h1p)[t] = uint4{0, 0, 0, 0};
    const float* xb = x + (size_t)b * 784;
    for (int t = tid; t < 784; t += 256) sm_xb[t] = f2bf(xb[t]);
    __syncthreads();

    // build 4 shifted copies: copy s pos p holds col c = p + s - 4 (0 outside)
    if (tid < 116) {
        int s = tid / 29;
        int r = tid - s * 29;
        unsigned short* dst = sm4 + (s * 29 + r) * 44;
        bool rok = r < 28;
#pragma unroll
        for (int g = 0; g < 11; ++g) {
            short4v v;
#pragma unroll
            for (int e = 0; e < 4; ++e) {
                int c = g * 4 + e + s - 4;
                v[e] = (short)((rok && (unsigned)c < 28u) ? sm_xb[r * 28 + c]
                                                          : (unsigned short)0);
            }
            *(short4v*)(dst + g * 4) = v;
        }
    }

    // conv1 A-frags + biases (global, L2-hot)
    short8 a1[2], a2[2];
    float bias1[2][4];
#pragma unroll
    for (int cot = 0; cot < 2; ++cot) {
        a1[cot] = *(const short8*)(K1a + (0 * 32 + cot * 16 + n16) * 32 + cig * 8);
        a2[cot] = *(const short8*)(K1a + (1 * 32 + cot * 16 + n16) * 32 + cig * 8);
#pragma unroll
        for (int r = 0; r < 4; ++r) bias1[cot][r] = b1[cot * 16 + 4 * cig + r];
    }
    __syncthreads();

    // ---- conv1 MFMA: 56 n-tiles (14 row-pairs x 4 col-eighths), wave-split ----
    {
        const int y = (n16 >> 3);
        const int xl = (n16 & 7);
#pragma unroll 2
        for (int t14 = 0; t14 < 14; ++t14) {
            int t = wv + 4 * t14;   // 0..55
            int ty = t >> 2;        // row pair 0..13
            int xh = t & 3;         // col group 0..3
            int yy = 2 * ty + y;    // 0..27
            int xx = 8 * xh + xl;   // 0..31 (28..31 phantom)
            int t0 = xx + 2;        // c0 + 4
            int s = t0 & 3;
            int p0 = t0 & ~3;
            const unsigned short* base = sm4 + s * (29 * 44) + p0;
            int row1 = yy - 2 + cig;
            int row2 = yy + 2 + cig;
            int r1 = ((unsigned)row1 < 28u) ? row1 : 28;  // 28 = zero row
            int r2 = ((unsigned)row2 < 28u) ? row2 : 28;
            short4v lo1 = *(const short4v*)(base + r1 * 44);
            short4v hi1 = *(const short4v*)(base + r1 * 44 + 4);
            short4v lo2 = *(const short4v*)(base + r2 * 44);
            short4v hi2 = *(const short4v*)(base + r2 * 44 + 4);
            short8 bf1 = {lo1[0], lo1[1], lo1[2], lo1[3], hi1[0], hi1[1], hi1[2], hi1[3]};
            short8 bf2 = {lo2[0], lo2[1], lo2[2], lo2[3], hi2[0], hi2[1], hi2[2], hi2[3]};

#pragma unroll
            for (int cot = 0; cot < 2; ++cot) {
                float4v acc = {0.f, 0.f, 0.f, 0.f};
                acc = __builtin_amdgcn_mfma_f32_16x16x32_bf16(a1[cot], bf1, acc, 0, 0, 0);
                acc = __builtin_amdgcn_mfma_f32_16x16x32_bf16(a2[cot], bf2, acc, 0, 0, 0);
#pragma unroll
                for (int r = 0; r < 4; ++r) {
                    float v = pool_max(acc[r]);
                    if ((n16 & 9) == 0) {
                        int xo = 4 * xh + (n16 >> 1);  // pooled col 0..15
                        if (xo < 14) {
                            int co = cot * 16 + 4 * cig + r;
                            h1p[((ty + 2) * 20 + (xo + 2)) * 40 + co] =
                                f2bf(fmaxf(v + bias1[cot][r], 0.f));
                        }
                    }
                }
            }
        }
    }
    __syncthreads();

    // ---- conv2: wave wv owns nt in {wv, wv+4, wv+8, wv+12} (nt<14) ----
    int ybase[4], xbase[4], ty_a[4], xh_a[4];
    bool valid[4];
#pragma unroll
    for (int ntl = 0; ntl < 4; ++ntl) {
        int nt = wv + 4 * ntl;
        valid[ntl] = nt < 14;
        int nts = valid[ntl] ? nt : 0;
        int ty = nts >> 1, xh = nts & 1;
        ty_a[ntl] = ty; xh_a[ntl] = xh;
        ybase[ntl] = 2 * ty + (n16 >> 3);
        xbase[ntl] = 8 * xh + (n16 & 7);
    }

    float4v acc[4][4];  // [ntl][cot] -> 64 AGPR
#pragma unroll
    for (int i = 0; i < 4; ++i)
#pragma unroll
        for (int c = 0; c < 4; ++c) acc[i][c] = float4v{0.f, 0.f, 0.f, 0.f};

#pragma unroll
    for (int ky = 0; ky < 5; ++ky) {
#pragma unroll
        for (int kx = 0; kx < 5; ++kx) {
            int kk = ky * 5 + kx;
            short8 afr[4];
#pragma unroll
            for (int cot = 0; cot < 4; ++cot)
                afr[cot] = *(const short8*)(Kt + ((kk * 64 + cot * 16 + n16) * 32 + cig * 8));
#pragma unroll
            for (int ntl = 0; ntl < 4; ++ntl) {
                if (valid[ntl]) {
                    short8 bf = *(const short8*)(h1p +
                        ((ybase[ntl] + ky) * 20 + xbase[ntl] + kx) * 40 + cig * 8);
#pragma unroll
                    for (int cot = 0; cot < 4; ++cot)
                        acc[ntl][cot] = __builtin_amdgcn_mfma_f32_16x16x32_bf16(
                            afr[cot], bf, acc[ntl][cot], 0, 0, 0);
                }
            }
        }
    }

    unsigned short* outb = h2 + (size_t)b * 3136;
#pragma unroll
    for (int ntl = 0; ntl < 4; ++ntl) {
        if (valid[ntl]) {
#pragma unroll
            for (int cot = 0; cot < 4; ++cot) {
#pragma unroll
                for (int r = 0; r < 4; ++r) {
                    float v = pool_max(acc[ntl][cot][r]);
                    if ((n16 & 9) == 0) {
                        int xo = 4 * xh_a[ntl] + (n16 >> 1);
                        if (xo < 7) {
                            int co = cot * 16 + 4 * cig + r;
                            outb[co * 49 + ty_a[ntl] * 7 + xo] =
                                f2bf(fmaxf(v + b2[co], 0.f));
                        }
                    }
                }
            }
        }
    }
}

// ---------------------------------------------------------------------------
// FC1 MFMA: out(B,128) += A(B,3136)bf16 @ W(128,3136)bf16^T  (K-split 7, atomics)
__global__ __launch_bounds__(256) void fc1_mfma(
    const unsigned short* __restrict__ A,
    const unsigned short* __restrict__ Wb,
    float* __restrict__ out) {  // pre-zeroed; bias applied in fc2
    const int blk = blockIdx.x;
    const int kh = blk % 7;
    const int m0 = (blk / 7) * 16;
    const int tid = threadIdx.x;
    const int wv = tid >> 6;
    const int lane = tid & 63;
    const int n16 = lane & 15;
    const int cig = lane >> 4;

    const unsigned short* Arow = A + (size_t)(m0 + n16) * 3136 + cig * 8 + kh * 448;
    const unsigned short* W0 = Wb + (size_t)(wv * 32 + n16) * 3136 + cig * 8 + kh * 448;
    const unsigned short* W1 = W0 + 16 * 3136;

    float4v acc0 = {0.f, 0.f, 0.f, 0.f};
    float4v acc1 = {0.f, 0.f, 0.f, 0.f};
#pragma unroll 7
    for (int k = 0; k < 448; k += 32) {
        short8 a = *(const short8*)(Arow + k);
        short8 w0 = *(const short8*)(W0 + k);
        short8 w1 = *(const short8*)(W1 + k);
        acc0 = __builtin_amdgcn_mfma_f32_16x16x32_bf16(a, w0, acc0, 0, 0, 0);
        acc1 = __builtin_amdgcn_mfma_f32_16x16x32_bf16(a, w1, acc1, 0, 0, 0);
    }
#pragma unroll
    for (int r = 0; r < 4; ++r) {
        int row = m0 + cig * 4 + r;
        atomicAdd(&out[(size_t)row * 128 + wv * 32 + n16], acc0[r]);
        atomicAdd(&out[(size_t)row * 128 + wv * 32 + 16 + n16], acc1[r]);
    }
}

// FC2 (fused fc1 bias+relu): out(B,10) = relu(fc1o + fc1b) @ W(10,128)^T + b2
__global__ __launch_bounds__(256) void fc2_kernel(
    const float* __restrict__ A, const float* __restrict__ fc1b,
    const float* __restrict__ W, const float* __restrict__ bias,
    float* __restrict__ out, int total) {
    __shared__ float smW[10 * 132];
    __shared__ float smB1[128];
    __shared__ float smB[10];
    int t = threadIdx.x;
    for (int i = t; i < 1280; i += 256) {
        int n = i >> 7, k = i & 127;
        smW[n * 132 + k] = W[i];
    }
    if (t < 128) smB1[t] = fc1b[t];
    if (t < 10) smB[t] = bias[t];
    __syncthreads();
    int idx = blockIdx.x * 256 + t;
    if (idx < total) {
        int b = idx / 10;
        int n = idx - b * 10;
        const float4* row = (const float4*)(A + (size_t)b * 128);
        const float4* bb = (const float4*)smB1;
        const float4* wr = (const float4*)(smW + n * 132);
        float acc = smB[n];
#pragma unroll
        for (int k = 0; k < 32; ++k) {
            float4 a = row[k];
            float4 bv = bb[k];
            float4 w = wr[k];
            acc += fmaxf(a.x + bv.x, 0.f) * w.x + fmaxf(a.y + bv.y, 0.f) * w.y +
                   fmaxf(a.z + bv.z, 0.f) * w.z + fmaxf(a.w + bv.w, 0.f) * w.w;
        }
        out[idx] = acc;
    }
}

extern "C" void kernel_launch(void* const* d_in, const int* in_sizes, int n_in,
                              void* d_out, int out_size, void* d_ws, size_t ws_size,
                              hipStream_t stream) {
    const float* x    = (const float*)d_in[0];
    const float* w1   = (const float*)d_in[1];
    const float* p1   = (const float*)d_in[2];
    const float* b1   = (const float*)d_in[3];
    const float* w2   = (const float*)d_in[4];
    const float* p2   = (const float*)d_in[5];
    const float* b2   = (const float*)d_in[6];
    const float* fc1w = (const float*)d_in[7];
    const float* fc1b = (const float*)d_in[8];
    const float* fc2w = (const float*)d_in[9];
    const float* fc2b = (const float*)d_in[10];
    float* out = (float*)d_out;

    const int B = in_sizes[0] / 784;  // 4096

    float* ws = (float*)d_ws;
    unsigned short* Kt  = (unsigned short*)ws;             // 51200 bf16 (25600 f)
    unsigned short* K1a = (unsigned short*)(ws + 25600);   // 2048 bf16 (1024 f)
    unsigned short* w1b = (unsigned short*)(ws + 26624);   // 401408 bf16 (200704 f)
    unsigned short* h2b = (unsigned short*)(ws + 227328);  // B*3136 bf16
    float* fc1o = ws + 227328 + (size_t)B * 1568;          // B*128 f32

    prep_all<<<1801, 256, 0, stream>>>(w1, p1, w2, p2, fc1w, K1a, Kt, w1b, fc1o);
    fused_conv_mfma<<<B, 256, 0, stream>>>(x, K1a, Kt, b1, b2, h2b);
    fc1_mfma<<<(B / 16) * 7, 256, 0, stream>>>(h2b, w1b, fc1o);
    fc2_kernel<<<(B * 10 + 255) / 256, 256, 0, stream>>>(fc1o, fc1b, fc2w, fc2b, out, B * 10);
}

// Round 7
// 257.498 us; speedup vs baseline: 1.4684x; 1.1775x over previous
//
#include <hip/hip_runtime.h>
#include <hip/hip_bf16.h>

typedef __attribute__((ext_vector_type(8))) short short8;
typedef __attribute__((ext_vector_type(4))) short short4v;
typedef __attribute__((ext_vector_type(4))) float float4v;

static __device__ __forceinline__ unsigned short f2bf(float f) {
    unsigned u = __float_as_uint(f);
    unsigned r = (u + 0x7FFF + ((u >> 16) & 1)) >> 16;  // RNE
    return (unsigned short)r;
}

// ---------------------------------------------------------------------------
// ONE prep kernel; every output buffer fully written by exactly one branch.
//  [0,8)     : K1b[co][k64] bf16 (DCLS gather, conv1 B-operand layout)
//  [8,208)   : Kt[kk][co][ci] bf16 (DCLS gather, conv2 B-operand layout)
//  [208,404) : fc1w fp32 -> w1b bf16 (native (128,3136) layout)
// ---------------------------------------------------------------------------
__global__ __launch_bounds__(256) void prep_all(
    const float* __restrict__ w1, const float* __restrict__ p1,
    const float* __restrict__ w2, const float* __restrict__ p2,
    const float* __restrict__ fc1w,
    unsigned short* __restrict__ K1b,   // (32,64)
    unsigned short* __restrict__ Kt,    // (25,64,32)
    unsigned short* __restrict__ w1b) { // (128,3136)
    const int blk = blockIdx.x;
    const int t = threadIdx.x;

    if (blk < 8) {
        // conv1 weights, B-layout: K1b[co][k], k = wr*8 + kx (zero-padded taps)
        int cell = blk * 256 + t;          // 0..2047
        int co = cell >> 6;
        int k = cell & 63;
        int wr = k >> 3;
        int kx = k & 7;
        float acc = 0.f;
        if (wr < 5 && kx < 5) {
#pragma unroll 8
            for (int kc = 0; kc < 16; ++kc) {
                float wv = w1[co * 16 + kc];
                float pa = p1[co * 16 + kc];
                float pb = p1[512 + co * 16 + kc];
                float pos1 = fminf(fmaxf(pa, -2.f), 2.f) + 2.f;
                float pos2 = fminf(fmaxf(pb, -2.f), 2.f) + 2.f;
                int i1 = (int)floorf(pos1);
                int i2 = (int)floorf(pos2);
                float r1 = pos1 - (float)i1;
                float r2 = pos2 - (float)i2;
                float c = 0.f;
                if (i1 == wr && i2 == kx) c += (1.f - r1) * (1.f - r2);
                if (i1 + 1 == wr && i2 == kx) c += r1 * (1.f - r2);
                if (i1 == wr && i2 + 1 == kx) c += (1.f - r1) * r2;
                if (i1 + 1 == wr && i2 + 1 == kx) c += r1 * r2;
                acc += wv * c;
            }
        }
        K1b[cell] = f2bf(acc);
    } else if (blk < 208) {
        int cell = (blk - 8) * 256 + t;    // 0..51199
        int kk = cell >> 11;
        int co = (cell >> 5) & 63;
        int ci = cell & 31;
        int ky = kk / 5;
        int kx = kk - 5 * ky;
        const int base = (co * 32 + ci) * 32;
        float acc = 0.f;
#pragma unroll 8
        for (int kc = 0; kc < 32; ++kc) {
            float wv = w2[base + kc];
            float pa = p2[base + kc];
            float pb = p2[65536 + base + kc];
            float pos1 = fminf(fmaxf(pa, -2.f), 2.f) + 2.f;
            float pos2 = fminf(fmaxf(pb, -2.f), 2.f) + 2.f;
            int i1 = (int)floorf(pos1);
            int i2 = (int)floorf(pos2);
            float r1 = pos1 - (float)i1;
            float r2 = pos2 - (float)i2;
            float c = 0.f;
            if (i1 == ky && i2 == kx) c += (1.f - r1) * (1.f - r2);
            if (i1 + 1 == ky && i2 == kx) c += r1 * (1.f - r2);
            if (i1 == ky && i2 + 1 == kx) c += (1.f - r1) * r2;
            if (i1 + 1 == ky && i2 + 1 == kx) c += r1 * r2;
            acc += wv * c;
        }
        Kt[cell] = f2bf(acc);
    } else {
        int i8 = ((blk - 208) * 256 + t) * 8;  // < 401408 exactly (196 blocks)
        float4 v0 = *(const float4*)(fc1w + i8);
        float4 v1 = *(const float4*)(fc1w + i8 + 4);
        short8 o = {(short)f2bf(v0.x), (short)f2bf(v0.y), (short)f2bf(v0.z),
                    (short)f2bf(v0.w), (short)f2bf(v1.x), (short)f2bf(v1.y),
                    (short)f2bf(v1.z), (short)f2bf(v1.w)};
        *(short8*)(w1b + i8) = o;
    }
}

// ---------------------------------------------------------------------------
// Fused conv, both on MFMA with POSITIONS ON THE A-SIDE: D rows (cig*4+r) of a
// lane = one 2x2 pool quad -> pooling = 3 in-lane fmax; every lane emits one
// pooled output (no wasted lanes, no cross-lane shuffles).
// conv1: 7x7 tiles of 4x4 px (zero phantom), K=64 taps = 2 MFMAs x 2 co-tiles;
//        weights = register-resident B-frags; image rows via 4 phase-shifted
//        LDS copies (2x ds_read_b64, zero-row clamp for borders).
// conv2: 16 tiles of 4x4 px over pooled 8x8 (49/64 valid), 25-tap shift-GEMM,
//        K=32 ci; A-frag = ds_read_b128 from h1p with immediate tap offsets;
//        B-frag = Kt from global (L2-hot).
// One block (4 waves) per image; LDS 40.5 KB -> 4 blocks/CU.
// ---------------------------------------------------------------------------
__global__ __launch_bounds__(256, 4) void fused_conv_mfma(
    const float* __restrict__ x,             // (B,1,28,28) fp32
    const unsigned short* __restrict__ K1b,  // (32,64)
    const unsigned short* __restrict__ Kt,   // (25,64,32)
    const float* __restrict__ b1,
    const float* __restrict__ b2,
    unsigned short* __restrict__ h2) {       // (B,3136) bf16
    __shared__ __align__(16) unsigned short h1p[18 * 20 * 40];  // [yy][xx][ci(+pad)]
    __shared__ __align__(16) unsigned short sm4[4 * 29 * 44];   // 4 shifted copies; row 28 zero
    __shared__ __align__(16) unsigned short sm_xb[784];

    const int b = blockIdx.x;
    const int tid = threadIdx.x;
    const int lane = tid & 63;
    const int wv = tid >> 6;
    const int n16 = lane & 15;
    const int cig = lane >> 4;

    // input-position offsets (A-side m = n16): quad + in-quad
    const int yi = 2 * (n16 >> 3) + ((n16 >> 1) & 1);  // 0..3
    const int xi = 2 * ((n16 >> 2) & 1) + (n16 & 1);   // 0..3
    // output pooled offsets (D rows: quad = cig)
    const int pYo = cig >> 1, pXo = cig & 1;

    // 1) zero h1p (borders + ci-pads must be 0) + stage image as bf16
    for (int t = tid; t < 1800; t += 256) ((uint4*)h1p)[t] = uint4{0, 0, 0, 0};
    {
        const float* xb = x + (size_t)b * 784;
        for (int t = tid; t < 784; t += 256) sm_xb[t] = f2bf(xb[t]);
    }
    __syncthreads();

    // 2) build 4 shifted copies (copy s pos p = pixel col p+s-4; row 28 = zeros)
    if (tid < 116) {
        int s = tid / 29;
        int r = tid - s * 29;
        unsigned short* dst = sm4 + (s * 29 + r) * 44;
        bool rok = r < 28;
#pragma unroll
        for (int g = 0; g < 11; ++g) {
            short4v v;
#pragma unroll
            for (int e = 0; e < 4; ++e) {
                int c = g * 4 + e + s - 4;
                v[e] = (short)((rok && (unsigned)c < 28u) ? sm_xb[r * 28 + c]
                                                          : (unsigned short)0);
            }
            *(short4v*)(dst + g * 4) = v;
        }
    }

    // conv1 weight B-frags (register-resident) + biases
    short8 bw[2][2];
    float bias1[2], bias2[4];
#pragma unroll
    for (int cot = 0; cot < 2; ++cot) {
#pragma unroll
        for (int h = 0; h < 2; ++h)
            bw[cot][h] = *(const short8*)(K1b + (cot * 16 + n16) * 64 + h * 32 + cig * 8);
        bias1[cot] = b1[cot * 16 + n16];
    }
#pragma unroll
    for (int cot = 0; cot < 4; ++cot) bias2[cot] = b2[cot * 16 + n16];

    // per-lane constant part of sm4 address (4tX is always 0 mod 4)
    const int s1 = (xi + 2) & 3;
    const int pb1 = (xi + 2) & ~3;
    const unsigned short* a1base = sm4 + s1 * (29 * 44) + pb1;

    __syncthreads();

    // 3) conv1: 49 tiles (7x7 of 4x4 px), wave-split; 4 MFMA + 2 stores/tile
    for (int i = 0; i < 13; ++i) {
        int t = wv + 4 * i;
        if (t < 49) {
            int tY = t / 7, tX = t - 7 * tY;
            const unsigned short* ab = a1base + 4 * tX;
            int r0 = 4 * tY + yi - 2 + cig;           // window rows 0..3
            int r1 = r0 + 4;                          // window rows 4..7
            int rr0 = ((unsigned)r0 < 28u) ? r0 : 28; // 28 = zero row
            int rr1 = ((unsigned)r1 < 28u) ? r1 : 28;
            short4v lo0 = *(const short4v*)(ab + rr0 * 44);
            short4v hi0 = *(const short4v*)(ab + rr0 * 44 + 4);
            short4v lo1 = *(const short4v*)(ab + rr1 * 44);
            short4v hi1 = *(const short4v*)(ab + rr1 * 44 + 4);
            short8 af0 = {lo0[0], lo0[1], lo0[2], lo0[3], hi0[0], hi0[1], hi0[2], hi0[3]};
            short8 af1 = {lo1[0], lo1[1], lo1[2], lo1[3], hi1[0], hi1[1], hi1[2], hi1[3]};
            int pY = 2 * tY + pYo, pX = 2 * tX + pXo;
#pragma unroll
            for (int cot = 0; cot < 2; ++cot) {
                float4v acc = {0.f, 0.f, 0.f, 0.f};
                acc = __builtin_amdgcn_mfma_f32_16x16x32_bf16(af0, bw[cot][0], acc, 0, 0, 0);
                acc = __builtin_amdgcn_mfma_f32_16x16x32_bf16(af1, bw[cot][1], acc, 0, 0, 0);
                float v = fmaxf(fmaxf(acc[0], acc[1]), fmaxf(acc[2], acc[3]));
                v = fmaxf(v + bias1[cot], 0.f);
                h1p[((pY + 2) * 20 + (pX + 2)) * 40 + cot * 16 + n16] = f2bf(v);
            }
        }
    }
    __syncthreads();

    // 4) conv2: wave owns 4 tiles (16 tiles of 4x4 px over pooled 8x8)
    const unsigned short* Ab[4];
    int pY2[4], pX2[4];
#pragma unroll
    for (int i = 0; i < 4; ++i) {
        int t = wv * 4 + i;
        int tY = t >> 2, tX = t & 3;
        int y2 = 4 * tY + yi;
        y2 = (y2 > 13) ? 13 : y2;   // phantom rows clamped (results discarded)
        int x2 = 4 * tX + xi;       // <=15, +kx fits cols 20
        Ab[i] = h1p + (y2 * 20 + x2) * 40 + cig * 8;
        pY2[i] = 2 * tY + pYo;
        pX2[i] = 2 * tX + pXo;
    }

    float4v acc[4][4];  // [tile][cot] = 64 AGPR
#pragma unroll
    for (int i = 0; i < 4; ++i)
#pragma unroll
        for (int c = 0; c < 4; ++c) acc[i][c] = float4v{0.f, 0.f, 0.f, 0.f};

#pragma unroll
    for (int ky = 0; ky < 5; ++ky) {
#pragma unroll
        for (int kx = 0; kx < 5; ++kx) {
            int kk = ky * 5 + kx;
            short8 wf[4];
#pragma unroll
            for (int cot = 0; cot < 4; ++cot)
                wf[cot] = *(const short8*)(Kt + ((kk * 64 + cot * 16 + n16) * 32 + cig * 8));
#pragma unroll
            for (int i = 0; i < 4; ++i) {
                short8 af = *(const short8*)(Ab[i] + (ky * 20 + kx) * 40);
#pragma unroll
                for (int cot = 0; cot < 4; ++cot)
                    acc[i][cot] = __builtin_amdgcn_mfma_f32_16x16x32_bf16(
                        af, wf[cot], acc[i][cot], 0, 0, 0);
            }
        }
    }

    unsigned short* outb = h2 + (size_t)b * 3136;
#pragma unroll
    for (int i = 0; i < 4; ++i) {
        bool ok = (pY2[i] < 7) & (pX2[i] < 7);
#pragma unroll
        for (int cot = 0; cot < 4; ++cot) {
            float4v a = acc[i][cot];
            float v = fmaxf(fmaxf(a[0], a[1]), fmaxf(a[2], a[3]));
            v = fmaxf(v + bias2[cot], 0.f);
            if (ok)
                outb[(cot * 16 + n16) * 49 + pY2[i] * 7 + pX2[i]] = f2bf(v);
        }
    }
}

// ---------------------------------------------------------------------------
// FC1 MFMA: partials[kh](B,128) = A(B,3136)bf16 @ W(128,3136)bf16^T slice kh.
// K-split 7 x 448; plain stores (no atomics, no pre-zero). 16 rows/block.
__global__ __launch_bounds__(256) void fc1_mfma(
    const unsigned short* __restrict__ A,
    const unsigned short* __restrict__ Wb,
    float* __restrict__ part, size_t PB) {  // PB = B*128
    const int blk = blockIdx.x;
    const int kh = blk % 7;
    const int m0 = (blk / 7) * 16;
    const int tid = threadIdx.x;
    const int wv = tid >> 6;
    const int lane = tid & 63;
    const int n16 = lane & 15;
    const int cig = lane >> 4;

    const unsigned short* Arow = A + (size_t)(m0 + n16) * 3136 + cig * 8 + kh * 448;
    const unsigned short* W0 = Wb + (size_t)(wv * 32 + n16) * 3136 + cig * 8 + kh * 448;
    const unsigned short* W1 = W0 + 16 * 3136;

    float4v acc0 = {0.f, 0.f, 0.f, 0.f};
    float4v acc1 = {0.f, 0.f, 0.f, 0.f};
#pragma unroll 7
    for (int k = 0; k < 448; k += 32) {
        short8 a = *(const short8*)(Arow + k);
        short8 w0 = *(const short8*)(W0 + k);
        short8 w1 = *(const short8*)(W1 + k);
        acc0 = __builtin_amdgcn_mfma_f32_16x16x32_bf16(a, w0, acc0, 0, 0, 0);
        acc1 = __builtin_amdgcn_mfma_f32_16x16x32_bf16(a, w1, acc1, 0, 0, 0);
    }
    float* o = part + (size_t)kh * PB;
#pragma unroll
    for (int r = 0; r < 4; ++r) {
        int row = m0 + cig * 4 + r;
        o[(size_t)row * 128 + wv * 32 + n16] = acc0[r];
        o[(size_t)row * 128 + wv * 32 + 16 + n16] = acc1[r];
    }
}

// FC2: out(B,10) = relu(sum of 7 fc1 partials + fc1b) @ W(10,128)^T + b2
__global__ __launch_bounds__(256) void fc2_kernel(
    const float* __restrict__ part, size_t PB,
    const float* __restrict__ fc1b,
    const float* __restrict__ W, const float* __restrict__ bias,
    float* __restrict__ out, int total) {
    __shared__ float smW[10 * 132];  // padded stride kills bank conflicts
    __shared__ float smB1[128];
    __shared__ float smB[10];
    int t = threadIdx.x;
    for (int i = t; i < 1280; i += 256) {
        int n = i >> 7, k = i & 127;
        smW[n * 132 + k] = W[i];
    }
    if (t < 128) smB1[t] = fc1b[t];
    if (t < 10) smB[t] = bias[t];
    __syncthreads();
    int idx = blockIdx.x * 256 + t;
    if (idx < total) {
        int b = idx / 10;
        int n = idx - b * 10;
        const float4* bb = (const float4*)smB1;
        const float4* wr = (const float4*)(smW + n * 132);
        float acc = smB[n];
#pragma unroll 4
        for (int k = 0; k < 32; ++k) {
            float4 s = *(const float4*)(part + (size_t)b * 128 + 4 * k);
#pragma unroll
            for (int j = 1; j < 7; ++j) {
                float4 pj = *(const float4*)(part + (size_t)j * PB + (size_t)b * 128 + 4 * k);
                s.x += pj.x; s.y += pj.y; s.z += pj.z; s.w += pj.w;
            }
            float4 bv = bb[k];
            float4 w = wr[k];
            acc += fmaxf(s.x + bv.x, 0.f) * w.x + fmaxf(s.y + bv.y, 0.f) * w.y +
                   fmaxf(s.z + bv.z, 0.f) * w.z + fmaxf(s.w + bv.w, 0.f) * w.w;
        }
        out[idx] = acc;
    }
}

extern "C" void kernel_launch(void* const* d_in, const int* in_sizes, int n_in,
                              void* d_out, int out_size, void* d_ws, size_t ws_size,
                              hipStream_t stream) {
    const float* x    = (const float*)d_in[0];
    const float* w1   = (const float*)d_in[1];
    const float* p1   = (const float*)d_in[2];
    const float* b1   = (const float*)d_in[3];
    const float* w2   = (const float*)d_in[4];
    const float* p2   = (const float*)d_in[5];
    const float* b2   = (const float*)d_in[6];
    const float* fc1w = (const float*)d_in[7];
    const float* fc1b = (const float*)d_in[8];
    const float* fc2w = (const float*)d_in[9];
    const float* fc2b = (const float*)d_in[10];
    float* out = (float*)d_out;

    const int B = in_sizes[0] / 784;  // 4096

    float* ws = (float*)d_ws;
    unsigned short* Kt  = (unsigned short*)ws;             // 51200 sh = 25600 f
    unsigned short* K1b = (unsigned short*)(ws + 25600);   // 2048 sh = 1024 f
    unsigned short* w1b = (unsigned short*)(ws + 26624);   // 401408 sh = 200704 f
    unsigned short* h2b = (unsigned short*)(ws + 227328);  // B*3136 sh = B*1568 f
    float* fc1p = ws + 227328 + (size_t)B * 1568;          // 7*B*128 f

    prep_all<<<404, 256, 0, stream>>>(w1, p1, w2, p2, fc1w, K1b, Kt, w1b);
    fused_conv_mfma<<<B, 256, 0, stream>>>(x, K1b, Kt, b1, b2, h2b);
    fc1_mfma<<<(B / 16) * 7, 256, 0, stream>>>(h2b, w1b, fc1p, (size_t)B * 128);
    fc2_kernel<<<(B * 10 + 255) / 256, 256, 0, stream>>>(fc1p, (size_t)B * 128,
                                                         fc1b, fc2w, fc2b, out, B * 10);
}